// Round 4
// baseline (152.212 us; speedup 1.0000x reference)
//
#include <hip/hip_runtime.h>
#include <math.h>

#define N_PTS 2048
#define M_PTS 128
#define INNF  256
#define H     128

#define MIN_STDC 0.30235680f   /* 0.32*1.88973/2 */
#define MAX_STDC 2.19208680f   /* 2.32*1.88973/2 */
#define PI_F     3.14159265358979f
#define LOG2E_F  1.44269504089f

static __device__ __forceinline__ float silu_f(float x) {
  return x / (1.0f + __expf(-x));
}

// ---------------------------------------------------------------------------
// K1 v2 (kept from R3, -2.5us): split-K across 8 half-wave k-slices.
// ---------------------------------------------------------------------------
__global__ __launch_bounds__(256) void k_pre(const float* __restrict__ h,
    const float* __restrict__ W_pre, const float* __restrict__ b_pre,
    const float* __restrict__ W_down, const float* __restrict__ gw,
    float* __restrict__ hdg4) {
  __shared__ float bigW[12288];
  __shared__ float red[8192];
  __shared__ float h_t[8 * INNF];
  __shared__ float hp_t[8 * H];
  int t = threadIdx.x;
  int n0 = blockIdx.x * 8;
  int wq = t & 31;
  int kw = t >> 5;
  int w0 = wq * 4;

  #pragma unroll
  for (int i = 0; i < 2; ++i) {
    int idx = t + i * 256;
    int row = idx >> 6, col = (idx & 63) << 2;
    *(float4*)&h_t[row * INNF + col] =
        *(const float4*)(h + (size_t)(n0 + row) * INNF + col);
  }

  // ---- GEMM1: hp = silu(h @ W_pre + b), k-split over kw ----
  float acc[8][4] = {};
  for (int kc = 0; kc < 256; kc += 64) {
    __syncthreads();
    #pragma unroll
    for (int i = 0; i < 8; ++i) {
      int idx = t + i * 256;
      *(float4*)&bigW[idx * 4] = *(const float4*)(W_pre + (size_t)kc * H + idx * 4);
    }
    __syncthreads();
    #pragma unroll
    for (int kk4 = 0; kk4 < 2; ++kk4) {
      int kb = kw * 8 + kk4 * 4;
      float4 hv[8];
      #pragma unroll
      for (int n = 0; n < 8; ++n)
        hv[n] = *(const float4*)&h_t[n * INNF + kc + kb];
      #pragma unroll
      for (int kk = 0; kk < 4; ++kk) {
        float4 wv = *(const float4*)&bigW[(kb + kk) * H + w0];
        #pragma unroll
        for (int n = 0; n < 8; ++n) {
          float hval = (kk == 0) ? hv[n].x : (kk == 1) ? hv[n].y
                     : (kk == 2) ? hv[n].z : hv[n].w;
          acc[n][0] += hval * wv.x; acc[n][1] += hval * wv.y;
          acc[n][2] += hval * wv.z; acc[n][3] += hval * wv.w;
        }
      }
    }
  }
  __syncthreads();
  #pragma unroll
  for (int n = 0; n < 8; ++n)
    *(float4*)&red[(kw * 8 + n) * 128 + w0] =
        make_float4(acc[n][0], acc[n][1], acc[n][2], acc[n][3]);
  __syncthreads();
  {
    int rn = t >> 5, rw = t & 31;
    float4 s = make_float4(0.0f, 0.0f, 0.0f, 0.0f);
    #pragma unroll
    for (int k2 = 0; k2 < 8; ++k2) {
      float4 v = *(const float4*)&red[(k2 * 8 + rn) * 128 + rw * 4];
      s.x += v.x; s.y += v.y; s.z += v.z; s.w += v.w;
    }
    float4 bv = *(const float4*)(b_pre + rw * 4);
    float4 o = make_float4(silu_f(s.x + bv.x), silu_f(s.y + bv.y),
                           silu_f(s.z + bv.z), silu_f(s.w + bv.w));
    *(float4*)&hp_t[rn * H + rw * 4] = o;
  }

  // ---- GEMM2: hp @ W_down[l], k-split over kw ----
  float acc2[3][8][4] = {};
  for (int kc = 0; kc < 128; kc += 32) {
    __syncthreads();
    #pragma unroll
    for (int i = 0; i < 12; ++i) {
      int idx = t + i * 256;
      int l = idx >> 10, r4 = idx & 1023;
      *(float4*)&bigW[idx * 4] =
          *(const float4*)(W_down + ((size_t)l * H + kc) * H + r4 * 4);
    }
    __syncthreads();
    {
      int kb = kw * 4;
      float4 hv[8];
      #pragma unroll
      for (int n = 0; n < 8; ++n)
        hv[n] = *(const float4*)&hp_t[n * H + kc + kb];
      #pragma unroll
      for (int kk = 0; kk < 4; ++kk) {
        #pragma unroll
        for (int l = 0; l < 3; ++l) {
          float4 wv = *(const float4*)&bigW[(l * 32 + kb + kk) * H + w0];
          #pragma unroll
          for (int n = 0; n < 8; ++n) {
            float hval = (kk == 0) ? hv[n].x : (kk == 1) ? hv[n].y
                       : (kk == 2) ? hv[n].z : hv[n].w;
            acc2[l][n][0] += hval * wv.x; acc2[l][n][1] += hval * wv.y;
            acc2[l][n][2] += hval * wv.z; acc2[l][n][3] += hval * wv.w;
          }
        }
      }
    }
  }

  __syncthreads();
  if (kw >= 4) {
    int s4 = kw - 4;
    #pragma unroll
    for (int l = 0; l < 3; ++l)
      #pragma unroll
      for (int n = 0; n < 8; ++n)
        *(float4*)&bigW[(s4 * 24 + l * 8 + n) * 128 + w0] =
            make_float4(acc2[l][n][0], acc2[l][n][1],
                        acc2[l][n][2], acc2[l][n][3]);
  }
  __syncthreads();
  if (kw < 4) {
    #pragma unroll
    for (int l = 0; l < 3; ++l)
      #pragma unroll
      for (int n = 0; n < 8; ++n) {
        float4 v = *(const float4*)&bigW[(kw * 24 + l * 8 + n) * 128 + w0];
        acc2[l][n][0] += v.x; acc2[l][n][1] += v.y;
        acc2[l][n][2] += v.z; acc2[l][n][3] += v.w;
      }
    if (kw >= 2) {
      int s2 = kw - 2;
      #pragma unroll
      for (int l = 0; l < 3; ++l)
        #pragma unroll
        for (int n = 0; n < 8; ++n)
          *(float4*)&red[(s2 * 24 + l * 8 + n) * 128 + w0] =
              make_float4(acc2[l][n][0], acc2[l][n][1],
                          acc2[l][n][2], acc2[l][n][3]);
    }
  }
  __syncthreads();
  if (kw < 2) {
    #pragma unroll
    for (int l = 0; l < 3; ++l)
      #pragma unroll
      for (int n = 0; n < 8; ++n) {
        float4 v = *(const float4*)&red[(kw * 24 + l * 8 + n) * 128 + w0];
        acc2[l][n][0] += v.x; acc2[l][n][1] += v.y;
        acc2[l][n][2] += v.z; acc2[l][n][3] += v.w;
      }
    if (kw == 1) {
      #pragma unroll
      for (int l = 0; l < 3; ++l)
        #pragma unroll
        for (int n = 0; n < 8; ++n)
          *(float4*)&bigW[(l * 8 + n) * 128 + w0] =
              make_float4(acc2[l][n][0], acc2[l][n][1],
                          acc2[l][n][2], acc2[l][n][3]);
    }
  }
  __syncthreads();
  if (kw == 0) {
    #pragma unroll
    for (int l = 0; l < 3; ++l)
      #pragma unroll
      for (int n = 0; n < 8; ++n) {
        float4 v = *(const float4*)&bigW[(l * 8 + n) * 128 + w0];
        acc2[l][n][0] += v.x; acc2[l][n][1] += v.y;
        acc2[l][n][2] += v.z; acc2[l][n][3] += v.w;
      }
    float gvals[8];
    #pragma unroll
    for (int n = 0; n < 8; ++n)
      gvals[n] = gw[n0 + n];
    const float stp = (MAX_STDC - MIN_STDC) / 127.0f;
    const float invn1 = 0.57735026919f, invn2 = 0.44721359550f;
    #pragma unroll
    for (int i = 0; i < 4; ++i) {
      int w = w0 + i;
      float s = MIN_STDC + (float)w * stp;
      float temps = 2.0f * s * s;
      float coef = (2.0f / 3.0f) / (temps * powf(PI_F * temps, 1.5f));
      #pragma unroll
      for (int n = 0; n < 8; ++n) {
        float sc = gvals[n] * coef;
        *(float4*)(hdg4 + ((size_t)(n0 + n) * H + w) * 4) =
            make_float4(acc2[0][n][i] * sc, acc2[1][n][i] * sc * invn1,
                        acc2[2][n][i] * sc * invn2, 0.0f);
      }
    }
  }
}

// ---------------------------------------------------------------------------
// K2 v7: mm-split half-waves, 4 w per lane. Lanes 0-31 and 32-63 cover the
// SAME 4-w columns but different mm pairs (hw: mm {0,1} vs {2,3}), so each
// sh ds_read_b128 feeds 4 w (was 2): LDS reads/thread 384 -> 192. hv global
// reads are full-wave broadcasts. acc[2][9][4] = 72 regs; no cross-lane
// reduce needed (half-waves own different outputs). Tree reduce unchanged.
// grid (32 mg, 16 s) = 512 blocks, 60 KB LDS -> 2 blocks/CU.
// ---------------------------------------------------------------------------
__global__ __launch_bounds__(256) void k_down(const float* __restrict__ gc,
    const float* __restrict__ cc, const float* __restrict__ hdg4,
    float* __restrict__ c_part) {
  __shared__ float sh_t[6144];    // [n_loc 0..127][m_loc 0..3][12]
  __shared__ float red[9216];     // 2 x 4608 tree-reduce buffers
  int t = threadIdx.x;
  int m0 = blockIdx.x * 4;
  int ss = blockIdx.y;            // 0..15
  int n0 = ss * 128;
  int wv = t >> 6;                // wave: n-chunk of 32
  int hw = (t >> 5) & 1;          // half-wave: mm-pair selector
  int lq = t & 31;
  int w0 = lq * 4;

  // phase 0: SH tile (128n x 4m) = 512 pairs, 2 per thread, b128 writes
  #pragma unroll
  for (int i = 0; i < 2; ++i) {
    int idx = t + i * 256;
    int n_loc = idx >> 2, m_loc = idx & 3;
    int n = n0 + n_loc, m = m0 + m_loc;
    float dx = gc[3*n]   - cc[3*m];
    float dy = gc[3*n+1] - cc[3*m+1];
    float dz = gc[3*n+2] - cc[3*m+2];
    float d2 = dx*dx + dy*dy + dz*dz + 3e-20f;
    float inv = rsqrtf(d2);
    float x = dx*inv, y = dy*inv, z = dz*inv;
    const float s3 = 1.73205080757f;
    float* dst = &sh_t[(size_t)idx * 12];
    *(float4*)(dst)     = make_float4(1.0f, x, y, z);
    *(float4*)(dst + 4) = make_float4(s3*x*z, s3*x*y,
                                      y*y - 0.5f*(x*x + z*z), s3*y*z);
    *(float4*)(dst + 8) = make_float4(0.5f*s3*(z*z - x*x), d2, 0.0f, 0.0f);
  }
  __syncthreads();

  const float stp = (MAX_STDC - MIN_STDC) / 127.0f;
  float cw[4];
  #pragma unroll
  for (int i = 0; i < 4; ++i) {
    float s = MIN_STDC + (float)(w0 + i) * stp;
    cw[i] = -LOG2E_F / (2.0f * s * s);
  }

  float acc[2][9][4] = {};    // [mmloc][li][w]
  for (int j = 0; j < 32; ++j) {
    int nl = wv * 32 + j;
    const float4* hb = (const float4*)(hdg4 + ((size_t)(n0 + nl) * H + w0) * 4);
    float4 hvv[4];
    hvv[0] = hb[0]; hvv[1] = hb[1]; hvv[2] = hb[2]; hvv[3] = hb[3];
    const float* shb = &sh_t[(size_t)nl * 48 + (size_t)hw * 24];
    #pragma unroll
    for (int ml = 0; ml < 2; ++ml) {
      float4 q0 = *(const float4*)(shb + ml*12);
      float4 q1 = *(const float4*)(shb + ml*12 + 4);
      float4 q2 = *(const float4*)(shb + ml*12 + 8);
      float d2v = q2.y;
      float rp[4];
      #pragma unroll
      for (int c = 0; c < 4; ++c)
        rp[c] = exp2f(d2v * cw[c]) * d2v;
      #pragma unroll
      for (int c = 0; c < 4; ++c) {
        float a0 = hvv[c].x * rp[c];
        float a1 = hvv[c].y * rp[c];
        float a2 = hvv[c].z * rp[c];
        acc[ml][0][c] += a0;
        acc[ml][1][c] += a1 * q0.y;
        acc[ml][2][c] += a1 * q0.z;
        acc[ml][3][c] += a1 * q0.w;
        acc[ml][4][c] += a2 * q1.x;
        acc[ml][5][c] += a2 * q1.y;
        acc[ml][6][c] += a2 * q1.z;
        acc[ml][7][c] += a2 * q1.w;
        acc[ml][8][c] += a2 * q2.x;
      }
    }
  }

  __syncthreads();
  if (wv & 1) {
    float* dst = &red[(wv >> 1) * 4608];
    #pragma unroll
    for (int ml = 0; ml < 2; ++ml)
      #pragma unroll
      for (int li = 0; li < 9; ++li)
        *(float4*)&dst[((hw*2 + ml)*9 + li)*128 + w0] =
            make_float4(acc[ml][li][0], acc[ml][li][1],
                        acc[ml][li][2], acc[ml][li][3]);
  }
  __syncthreads();
  if (!(wv & 1)) {
    const float* src = &red[(wv >> 1) * 4608];
    #pragma unroll
    for (int ml = 0; ml < 2; ++ml)
      #pragma unroll
      for (int li = 0; li < 9; ++li) {
        float4 v = *(const float4*)&src[((hw*2 + ml)*9 + li)*128 + w0];
        acc[ml][li][0] += v.x; acc[ml][li][1] += v.y;
        acc[ml][li][2] += v.z; acc[ml][li][3] += v.w;
      }
  }
  __syncthreads();
  if (wv == 2) {
    #pragma unroll
    for (int ml = 0; ml < 2; ++ml)
      #pragma unroll
      for (int li = 0; li < 9; ++li)
        *(float4*)&red[((hw*2 + ml)*9 + li)*128 + w0] =
            make_float4(acc[ml][li][0], acc[ml][li][1],
                        acc[ml][li][2], acc[ml][li][3]);
  }
  __syncthreads();
  if (wv == 0) {
    #pragma unroll
    for (int ml = 0; ml < 2; ++ml)
      #pragma unroll
      for (int li = 0; li < 9; ++li) {
        float4 v = *(const float4*)&red[((hw*2 + ml)*9 + li)*128 + w0];
        float4 o = make_float4(acc[ml][li][0] + v.x, acc[ml][li][1] + v.y,
                               acc[ml][li][2] + v.z, acc[ml][li][3] + v.w);
        *(float4*)&c_part[(((size_t)ss*M_PTS + m0 + hw*2 + ml)*9 + li)*H + w0] = o;
      }
  }
}

// ---------------------------------------------------------------------------
// K3: block = (m, li): sum 16 s-partials over u, contract with W_up.
// grid (128, 9) = 1152 blocks, 128 threads.
// ---------------------------------------------------------------------------
__global__ __launch_bounds__(128) void k_cu(const float* __restrict__ c_part,
    const float* __restrict__ W_up, float* __restrict__ CU9) {
  __shared__ float c_lds[H];
  int t = threadIdx.x;
  int m = blockIdx.x, li = blockIdx.y;
  float v = 0.0f;
  #pragma unroll
  for (int s = 0; s < 16; ++s)
    v += c_part[(((size_t)s*M_PTS + m)*9 + li)*H + t];
  c_lds[t] = v;
  __syncthreads();

  int l = (li == 0) ? 0 : (li < 4 ? 1 : 2);
  const float invn[3] = {1.0f, 0.57735026919f, 0.44721359550f};
  float acc = 0.0f;
  for (int u = 0; u < H; u += 4) {
    float w0 = W_up[((size_t)l*H + u + 0)*H + t];
    float w1 = W_up[((size_t)l*H + u + 1)*H + t];
    float w2 = W_up[((size_t)l*H + u + 2)*H + t];
    float w3 = W_up[((size_t)l*H + u + 3)*H + t];
    acc += c_lds[u]*w0 + c_lds[u+1]*w1 + c_lds[u+2]*w2 + c_lds[u+3]*w3;
  }
  CU9[((size_t)m*9 + li)*H + t] = acc * invn[l];
}

// ---------------------------------------------------------------------------
// K4 v3: register-B, ZERO LDS, same grid as v1 (64 n-blocks x 8 ks = 512
// blocks = 2/CU, the R2-lesson fix for v2's 1-block/CU collapse). B frags
// (9 x float4 per m) loaded straight from L2-hot CU9 into regs; sh computed
// in-register per (n,m); thread tile 4n x 4w. No barriers at all.
// ---------------------------------------------------------------------------
__global__ __launch_bounds__(256) void k_up(const float* __restrict__ gc,
    const float* __restrict__ cc, const float* __restrict__ CU9,
    float* __restrict__ out_part) {
  int t = threadIdx.x;
  int n0 = blockIdx.x * 32;
  int ks = blockIdx.y;                 // 0..7, m chunk = ks*16 .. +15
  int wq = t & 31;
  int ng = t >> 5;                     // 0..7 -> n base = n0 + ng*4
  int w0 = wq * 4;

  float gx[4], gy[4], gz[4];
  #pragma unroll
  for (int r = 0; r < 4; ++r) {
    int n = n0 + ng * 4 + r;
    gx[r] = gc[3*n]; gy[r] = gc[3*n+1]; gz[r] = gc[3*n+2];
  }

  float acc[4][4] = {};
  #pragma unroll 2
  for (int mr = 0; mr < 16; ++mr) {
    int m = ks * 16 + mr;
    float cx = cc[3*m], cy = cc[3*m+1], cz = cc[3*m+2];
    const float* Bp = CU9 + (size_t)m * 9 * H + w0;
    float4 B0 = *(const float4*)(Bp + 0*H);
    float4 B1 = *(const float4*)(Bp + 1*H);
    float4 B2 = *(const float4*)(Bp + 2*H);
    float4 B3 = *(const float4*)(Bp + 3*H);
    float4 B4 = *(const float4*)(Bp + 4*H);
    float4 B5 = *(const float4*)(Bp + 5*H);
    float4 B6 = *(const float4*)(Bp + 6*H);
    float4 B7 = *(const float4*)(Bp + 7*H);
    float4 B8 = *(const float4*)(Bp + 8*H);
    #pragma unroll
    for (int r = 0; r < 4; ++r) {
      float dx = gx[r]-cx, dy = gy[r]-cy, dz = gz[r]-cz;
      float d2 = dx*dx + dy*dy + dz*dz + 3e-20f;
      float inv = rsqrtf(d2);
      float x = dx*inv, y = dy*inv, z = dz*inv;
      const float s3 = 1.73205080757f;
      float s4 = s3*x*z, s5 = s3*x*y, s6 = y*y - 0.5f*(x*x + z*z);
      float s7 = s3*y*z, s8 = 0.5f*s3*(z*z - x*x);
      acc[r][0] += B0.x;        acc[r][1] += B0.y;
      acc[r][2] += B0.z;        acc[r][3] += B0.w;
      acc[r][0] += x*B1.x;      acc[r][1] += x*B1.y;
      acc[r][2] += x*B1.z;      acc[r][3] += x*B1.w;
      acc[r][0] += y*B2.x;      acc[r][1] += y*B2.y;
      acc[r][2] += y*B2.z;      acc[r][3] += y*B2.w;
      acc[r][0] += z*B3.x;      acc[r][1] += z*B3.y;
      acc[r][2] += z*B3.z;      acc[r][3] += z*B3.w;
      acc[r][0] += s4*B4.x;     acc[r][1] += s4*B4.y;
      acc[r][2] += s4*B4.z;     acc[r][3] += s4*B4.w;
      acc[r][0] += s5*B5.x;     acc[r][1] += s5*B5.y;
      acc[r][2] += s5*B5.z;     acc[r][3] += s5*B5.w;
      acc[r][0] += s6*B6.x;     acc[r][1] += s6*B6.y;
      acc[r][2] += s6*B6.z;     acc[r][3] += s6*B6.w;
      acc[r][0] += s7*B7.x;     acc[r][1] += s7*B7.y;
      acc[r][2] += s7*B7.z;     acc[r][3] += s7*B7.w;
      acc[r][0] += s8*B8.x;     acc[r][1] += s8*B8.y;
      acc[r][2] += s8*B8.z;     acc[r][3] += s8*B8.w;
    }
  }
  #pragma unroll
  for (int r = 0; r < 4; ++r) {
    size_t row = (size_t)ks*N_PTS + n0 + ng*4 + r;
    *(float4*)(out_part + row*H + w0) =
        make_float4(acc[r][0], acc[r][1], acc[r][2], acc[r][3]);
  }
}

// ---------------------------------------------------------------------------
// K5: reduce 8 split-K partials, post-MLP + silu -> d_out.
// ---------------------------------------------------------------------------
__global__ __launch_bounds__(256) void k_post(const float* __restrict__ out_part,
    const float* __restrict__ W_post, const float* __restrict__ b_post,
    float* __restrict__ out) {
  __shared__ float op[4 * H];
  int t = threadIdx.x;
  int n0 = blockIdx.x * 4;
  int w = t & 127, nh = t >> 7;

  #pragma unroll
  for (int i = 0; i < 2; ++i) {
    int idx = t + i*256;
    int nl = idx >> 7, ww = idx & 127;
    float v = 0.0f;
    #pragma unroll
    for (int s = 0; s < 8; ++s)
      v += out_part[((size_t)s*N_PTS + n0 + nl)*H + ww];
    op[nl*H + ww] = v;
  }
  __syncthreads();

  float acc[2] = {0.0f, 0.0f};
  for (int u = 0; u < H; u += 4) {
    float4 p0 = *(const float4*)&op[(nh*2 + 0)*H + u];
    float4 p1 = *(const float4*)&op[(nh*2 + 1)*H + u];
    float w0 = W_post[(u+0)*H + w];
    float w1 = W_post[(u+1)*H + w];
    float w2 = W_post[(u+2)*H + w];
    float w3 = W_post[(u+3)*H + w];
    acc[0] += p0.x*w0 + p0.y*w1 + p0.z*w2 + p0.w*w3;
    acc[1] += p1.x*w0 + p1.y*w1 + p1.z*w2 + p1.w*w3;
  }
  float bp = b_post[w];
  out[(size_t)(n0 + nh*2 + 0)*H + w] = silu_f(acc[0] + bp);
  out[(size_t)(n0 + nh*2 + 1)*H + w] = silu_f(acc[1] + bp);
}

// ---------------------------------------------------------------------------
extern "C" void kernel_launch(void* const* d_in, const int* in_sizes, int n_in,
                              void* d_out, int out_size, void* d_ws, size_t ws_size,
                              hipStream_t stream) {
  const float* h      = (const float*)d_in[0];
  const float* gc     = (const float*)d_in[1];
  const float* cc     = (const float*)d_in[2];
  const float* gw     = (const float*)d_in[3];
  const float* W_pre  = (const float*)d_in[4];
  const float* b_pre  = (const float*)d_in[5];
  const float* W_down = (const float*)d_in[6];
  const float* W_up   = (const float*)d_in[7];
  const float* W_post = (const float*)d_in[8];
  const float* b_post = (const float*)d_in[9];

  float* ws       = (float*)d_ws;
  float* hdg4     = ws;                     // 2048*128*4   = 1,048,576 f
  float* c_part   = hdg4 + 1048576;         // 16*128*9*128 = 2,359,296 f
  float* CU9      = c_part + 2359296;       // 128*9*128    =   147,456 f
  float* out_part = c_part;                 // 8*2048*128 = 2,097,152 f aliases
  float* out      = (float*)d_out;

  k_pre <<<256,           256, 0, stream>>>(h, W_pre, b_pre, W_down, gw, hdg4);
  k_down<<<dim3(32,16),   256, 0, stream>>>(gc, cc, hdg4, c_part);
  k_cu  <<<dim3(128,9),   128, 0, stream>>>(c_part, W_up, CU9);
  k_up  <<<dim3(64,8),    256, 0, stream>>>(gc, cc, CU9, out_part);
  k_post<<<512,           256, 0, stream>>>(out_part, W_post, b_post, out);
}

// Round 5
// 139.466 us; speedup vs baseline: 1.0914x; 1.0914x over previous
//
#include <hip/hip_runtime.h>
#include <math.h>

#define N_PTS 2048
#define M_PTS 128
#define INNF  256
#define H     128

#define MIN_STDC 0.30235680f   /* 0.32*1.88973/2 */
#define MAX_STDC 2.19208680f   /* 2.32*1.88973/2 */
#define PI_F     3.14159265358979f
#define LOG2E_F  1.44269504089f

static __device__ __forceinline__ float silu_f(float x) {
  return x / (1.0f + __expf(-x));
}

// ---------------------------------------------------------------------------
// K1 v2 (kept from R3, -2.5us): split-K across 8 half-wave k-slices.
// ---------------------------------------------------------------------------
__global__ __launch_bounds__(256) void k_pre(const float* __restrict__ h,
    const float* __restrict__ W_pre, const float* __restrict__ b_pre,
    const float* __restrict__ W_down, const float* __restrict__ gw,
    float* __restrict__ hdg4) {
  __shared__ float bigW[12288];
  __shared__ float red[8192];
  __shared__ float h_t[8 * INNF];
  __shared__ float hp_t[8 * H];
  int t = threadIdx.x;
  int n0 = blockIdx.x * 8;
  int wq = t & 31;
  int kw = t >> 5;
  int w0 = wq * 4;

  #pragma unroll
  for (int i = 0; i < 2; ++i) {
    int idx = t + i * 256;
    int row = idx >> 6, col = (idx & 63) << 2;
    *(float4*)&h_t[row * INNF + col] =
        *(const float4*)(h + (size_t)(n0 + row) * INNF + col);
  }

  // ---- GEMM1: hp = silu(h @ W_pre + b), k-split over kw ----
  float acc[8][4] = {};
  for (int kc = 0; kc < 256; kc += 64) {
    __syncthreads();
    #pragma unroll
    for (int i = 0; i < 8; ++i) {
      int idx = t + i * 256;
      *(float4*)&bigW[idx * 4] = *(const float4*)(W_pre + (size_t)kc * H + idx * 4);
    }
    __syncthreads();
    #pragma unroll
    for (int kk4 = 0; kk4 < 2; ++kk4) {
      int kb = kw * 8 + kk4 * 4;
      float4 hv[8];
      #pragma unroll
      for (int n = 0; n < 8; ++n)
        hv[n] = *(const float4*)&h_t[n * INNF + kc + kb];
      #pragma unroll
      for (int kk = 0; kk < 4; ++kk) {
        float4 wv = *(const float4*)&bigW[(kb + kk) * H + w0];
        #pragma unroll
        for (int n = 0; n < 8; ++n) {
          float hval = (kk == 0) ? hv[n].x : (kk == 1) ? hv[n].y
                     : (kk == 2) ? hv[n].z : hv[n].w;
          acc[n][0] += hval * wv.x; acc[n][1] += hval * wv.y;
          acc[n][2] += hval * wv.z; acc[n][3] += hval * wv.w;
        }
      }
    }
  }
  __syncthreads();
  #pragma unroll
  for (int n = 0; n < 8; ++n)
    *(float4*)&red[(kw * 8 + n) * 128 + w0] =
        make_float4(acc[n][0], acc[n][1], acc[n][2], acc[n][3]);
  __syncthreads();
  {
    int rn = t >> 5, rw = t & 31;
    float4 s = make_float4(0.0f, 0.0f, 0.0f, 0.0f);
    #pragma unroll
    for (int k2 = 0; k2 < 8; ++k2) {
      float4 v = *(const float4*)&red[(k2 * 8 + rn) * 128 + rw * 4];
      s.x += v.x; s.y += v.y; s.z += v.z; s.w += v.w;
    }
    float4 bv = *(const float4*)(b_pre + rw * 4);
    float4 o = make_float4(silu_f(s.x + bv.x), silu_f(s.y + bv.y),
                           silu_f(s.z + bv.z), silu_f(s.w + bv.w));
    *(float4*)&hp_t[rn * H + rw * 4] = o;
  }

  // ---- GEMM2: hp @ W_down[l], k-split over kw ----
  float acc2[3][8][4] = {};
  for (int kc = 0; kc < 128; kc += 32) {
    __syncthreads();
    #pragma unroll
    for (int i = 0; i < 12; ++i) {
      int idx = t + i * 256;
      int l = idx >> 10, r4 = idx & 1023;
      *(float4*)&bigW[idx * 4] =
          *(const float4*)(W_down + ((size_t)l * H + kc) * H + r4 * 4);
    }
    __syncthreads();
    {
      int kb = kw * 4;
      float4 hv[8];
      #pragma unroll
      for (int n = 0; n < 8; ++n)
        hv[n] = *(const float4*)&hp_t[n * H + kc + kb];
      #pragma unroll
      for (int kk = 0; kk < 4; ++kk) {
        #pragma unroll
        for (int l = 0; l < 3; ++l) {
          float4 wv = *(const float4*)&bigW[(l * 32 + kb + kk) * H + w0];
          #pragma unroll
          for (int n = 0; n < 8; ++n) {
            float hval = (kk == 0) ? hv[n].x : (kk == 1) ? hv[n].y
                       : (kk == 2) ? hv[n].z : hv[n].w;
            acc2[l][n][0] += hval * wv.x; acc2[l][n][1] += hval * wv.y;
            acc2[l][n][2] += hval * wv.z; acc2[l][n][3] += hval * wv.w;
          }
        }
      }
    }
  }

  __syncthreads();
  if (kw >= 4) {
    int s4 = kw - 4;
    #pragma unroll
    for (int l = 0; l < 3; ++l)
      #pragma unroll
      for (int n = 0; n < 8; ++n)
        *(float4*)&bigW[(s4 * 24 + l * 8 + n) * 128 + w0] =
            make_float4(acc2[l][n][0], acc2[l][n][1],
                        acc2[l][n][2], acc2[l][n][3]);
  }
  __syncthreads();
  if (kw < 4) {
    #pragma unroll
    for (int l = 0; l < 3; ++l)
      #pragma unroll
      for (int n = 0; n < 8; ++n) {
        float4 v = *(const float4*)&bigW[(kw * 24 + l * 8 + n) * 128 + w0];
        acc2[l][n][0] += v.x; acc2[l][n][1] += v.y;
        acc2[l][n][2] += v.z; acc2[l][n][3] += v.w;
      }
    if (kw >= 2) {
      int s2 = kw - 2;
      #pragma unroll
      for (int l = 0; l < 3; ++l)
        #pragma unroll
        for (int n = 0; n < 8; ++n)
          *(float4*)&red[(s2 * 24 + l * 8 + n) * 128 + w0] =
              make_float4(acc2[l][n][0], acc2[l][n][1],
                          acc2[l][n][2], acc2[l][n][3]);
    }
  }
  __syncthreads();
  if (kw < 2) {
    #pragma unroll
    for (int l = 0; l < 3; ++l)
      #pragma unroll
      for (int n = 0; n < 8; ++n) {
        float4 v = *(const float4*)&red[(kw * 24 + l * 8 + n) * 128 + w0];
        acc2[l][n][0] += v.x; acc2[l][n][1] += v.y;
        acc2[l][n][2] += v.z; acc2[l][n][3] += v.w;
      }
    if (kw == 1) {
      #pragma unroll
      for (int l = 0; l < 3; ++l)
        #pragma unroll
        for (int n = 0; n < 8; ++n)
          *(float4*)&bigW[(l * 8 + n) * 128 + w0] =
              make_float4(acc2[l][n][0], acc2[l][n][1],
                          acc2[l][n][2], acc2[l][n][3]);
    }
  }
  __syncthreads();
  if (kw == 0) {
    #pragma unroll
    for (int l = 0; l < 3; ++l)
      #pragma unroll
      for (int n = 0; n < 8; ++n) {
        float4 v = *(const float4*)&bigW[(l * 8 + n) * 128 + w0];
        acc2[l][n][0] += v.x; acc2[l][n][1] += v.y;
        acc2[l][n][2] += v.z; acc2[l][n][3] += v.w;
      }
    float gvals[8];
    #pragma unroll
    for (int n = 0; n < 8; ++n)
      gvals[n] = gw[n0 + n];
    const float stp = (MAX_STDC - MIN_STDC) / 127.0f;
    const float invn1 = 0.57735026919f, invn2 = 0.44721359550f;
    #pragma unroll
    for (int i = 0; i < 4; ++i) {
      int w = w0 + i;
      float s = MIN_STDC + (float)w * stp;
      float temps = 2.0f * s * s;
      float coef = (2.0f / 3.0f) / (temps * powf(PI_F * temps, 1.5f));
      #pragma unroll
      for (int n = 0; n < 8; ++n) {
        float sc = gvals[n] * coef;
        *(float4*)(hdg4 + ((size_t)(n0 + n) * H + w) * 4) =
            make_float4(acc2[0][n][i] * sc, acc2[1][n][i] * sc * invn1,
                        acc2[2][n][i] * sc * invn2, 0.0f);
      }
    }
  }
}

// ---------------------------------------------------------------------------
// K2 (exact R0/R3 v4): pair loop, 128 n per block (16 s-slices). 2 w per
// lane; 4 waves each own a private 32-n subchunk; 2-stage LDS tree reduce.
// grid (32 mg, 16 s) = 512 blocks, 60 KB LDS -> 2 blocks/CU. The sh reads
// are wave-uniform broadcasts (cheap) -- do NOT trade them for global reads.
// ---------------------------------------------------------------------------
__global__ __launch_bounds__(256) void k_down(const float* __restrict__ gc,
    const float* __restrict__ cc, const float* __restrict__ hdg4,
    float* __restrict__ c_part) {
  __shared__ float sh_t[6144];    // [n_loc 0..127][m_loc 0..3][12]
  __shared__ float red[9216];     // 2 x 4608 tree-reduce buffers
  int t = threadIdx.x;
  int m0 = blockIdx.x * 4;
  int ss = blockIdx.y;            // 0..15
  int n0 = ss * 128;
  int wv = t >> 6;
  int ln = t & 63;
  int w0 = ln * 2;

  // phase 0: SH tile (128n x 4m) = 512 pairs, 2 per thread
  #pragma unroll
  for (int i = 0; i < 2; ++i) {
    int idx = t + i * 256;
    int n_loc = idx >> 2, m_loc = idx & 3;
    int n = n0 + n_loc, m = m0 + m_loc;
    float dx = gc[3*n]   - cc[3*m];
    float dy = gc[3*n+1] - cc[3*m+1];
    float dz = gc[3*n+2] - cc[3*m+2];
    float d2 = dx*dx + dy*dy + dz*dz + 3e-20f;
    float inv = rsqrtf(d2);
    float x = dx*inv, y = dy*inv, z = dz*inv;
    const float s3 = 1.73205080757f;
    float* dst = &sh_t[(size_t)idx * 12];
    dst[0] = 1.0f; dst[1] = x; dst[2] = y; dst[3] = z;
    dst[4] = s3*x*z; dst[5] = s3*x*y; dst[6] = y*y - 0.5f*(x*x + z*z);
    dst[7] = s3*y*z; dst[8] = 0.5f*s3*(z*z - x*x);
    dst[9] = d2; dst[10] = 0.0f; dst[11] = 0.0f;
  }
  __syncthreads();

  const float stp = (MAX_STDC - MIN_STDC) / 127.0f;
  float sA = MIN_STDC + (float)w0 * stp;
  float sB = MIN_STDC + (float)(w0 + 1) * stp;
  float cA = -LOG2E_F / (2.0f * sA * sA);
  float cB = -LOG2E_F / (2.0f * sB * sB);

  float acc[4][9][2] = {};
  for (int j = 0; j < 32; ++j) {
    int nl = wv * 32 + j;
    const float4* hb = (const float4*)(hdg4 + ((size_t)(n0 + nl) * H + w0) * 4);
    float4 hv0 = hb[0];
    float4 hv1 = hb[1];
    const float* shb = &sh_t[(size_t)nl * 48];
    #pragma unroll
    for (int mm = 0; mm < 4; ++mm) {
      float4 q0 = *(const float4*)(shb + mm*12);
      float4 q1 = *(const float4*)(shb + mm*12 + 4);
      float4 q2 = *(const float4*)(shb + mm*12 + 8);
      float e0 = exp2f(q2.y * cA);
      float e1 = exp2f(q2.y * cB);
      float rp0 = e0 * q2.y, rp1 = e1 * q2.y;
      float a00 = hv0.x*rp0, a01 = hv0.y*rp0, a02 = hv0.z*rp0;
      float a10 = hv1.x*rp1, a11 = hv1.y*rp1, a12 = hv1.z*rp1;
      acc[mm][0][0] += a00;        acc[mm][0][1] += a10;
      acc[mm][1][0] += a01*q0.y;   acc[mm][1][1] += a11*q0.y;
      acc[mm][2][0] += a01*q0.z;   acc[mm][2][1] += a11*q0.z;
      acc[mm][3][0] += a01*q0.w;   acc[mm][3][1] += a11*q0.w;
      acc[mm][4][0] += a02*q1.x;   acc[mm][4][1] += a12*q1.x;
      acc[mm][5][0] += a02*q1.y;   acc[mm][5][1] += a12*q1.y;
      acc[mm][6][0] += a02*q1.z;   acc[mm][6][1] += a12*q1.z;
      acc[mm][7][0] += a02*q1.w;   acc[mm][7][1] += a12*q1.w;
      acc[mm][8][0] += a02*q2.x;   acc[mm][8][1] += a12*q2.x;
    }
  }

  __syncthreads();
  if (wv & 1) {
    float* dst = &red[(wv >> 1) * 4608];
    #pragma unroll
    for (int mm = 0; mm < 4; ++mm)
      #pragma unroll
      for (int li = 0; li < 9; ++li)
        *(float2*)&dst[(mm*9 + li)*128 + w0] =
            make_float2(acc[mm][li][0], acc[mm][li][1]);
  }
  __syncthreads();
  if (!(wv & 1)) {
    const float* src = &red[(wv >> 1) * 4608];
    #pragma unroll
    for (int mm = 0; mm < 4; ++mm)
      #pragma unroll
      for (int li = 0; li < 9; ++li) {
        float2 v = *(const float2*)&src[(mm*9 + li)*128 + w0];
        acc[mm][li][0] += v.x; acc[mm][li][1] += v.y;
      }
  }
  __syncthreads();
  if (wv == 2) {
    #pragma unroll
    for (int mm = 0; mm < 4; ++mm)
      #pragma unroll
      for (int li = 0; li < 9; ++li)
        *(float2*)&red[(mm*9 + li)*128 + w0] =
            make_float2(acc[mm][li][0], acc[mm][li][1]);
  }
  __syncthreads();
  if (wv == 0) {
    #pragma unroll
    for (int mm = 0; mm < 4; ++mm)
      #pragma unroll
      for (int li = 0; li < 9; ++li) {
        float2 v = *(const float2*)&red[(mm*9 + li)*128 + w0];
        float2 o = make_float2(acc[mm][li][0] + v.x, acc[mm][li][1] + v.y);
        *(float2*)&c_part[(((size_t)ss*M_PTS + m0 + mm)*9 + li)*H + w0] = o;
      }
  }
}

// ---------------------------------------------------------------------------
// K3 v2 (THE single change this round): l-grouped blocks. grid (128 m, 3 l),
// each block computes ALL li of its l (1/3/5 outputs) and reads the 64 KB
// W_up l-slice ONCE: W_up traffic 73 MB -> 24.6 MB. Compile-time li-count
// paths (templated) so acc[] stays in registers (rule #20).
// ---------------------------------------------------------------------------
template <int NLI, int LI0>
static __device__ __forceinline__ void k_cu_body(const float* __restrict__ c_part,
    const float* __restrict__ W_up, float* __restrict__ CU9,
    float* c_lds, int t, int m, int l) {
  #pragma unroll
  for (int i = 0; i < NLI; ++i) {
    float v = 0.0f;
    #pragma unroll
    for (int s = 0; s < 16; ++s)
      v += c_part[(((size_t)s*M_PTS + m)*9 + LI0 + i)*H + t];
    c_lds[i*H + t] = v;
  }
  __syncthreads();

  float acc[NLI];
  #pragma unroll
  for (int i = 0; i < NLI; ++i) acc[i] = 0.0f;
  for (int u = 0; u < H; u += 4) {
    float w0 = W_up[((size_t)l*H + u + 0)*H + t];
    float w1 = W_up[((size_t)l*H + u + 1)*H + t];
    float w2 = W_up[((size_t)l*H + u + 2)*H + t];
    float w3 = W_up[((size_t)l*H + u + 3)*H + t];
    #pragma unroll
    for (int i = 0; i < NLI; ++i)
      acc[i] += c_lds[i*H + u]*w0 + c_lds[i*H + u + 1]*w1
              + c_lds[i*H + u + 2]*w2 + c_lds[i*H + u + 3]*w3;
  }
  const float invn[3] = {1.0f, 0.57735026919f, 0.44721359550f};
  float sc = invn[l];
  #pragma unroll
  for (int i = 0; i < NLI; ++i)
    CU9[((size_t)m*9 + LI0 + i)*H + t] = acc[i] * sc;
}

__global__ __launch_bounds__(128) void k_cu(const float* __restrict__ c_part,
    const float* __restrict__ W_up, float* __restrict__ CU9) {
  __shared__ float c_lds[5 * H];
  int t = threadIdx.x;
  int m = blockIdx.x, l = blockIdx.y;        // l = 0,1,2
  if (l == 0)      k_cu_body<1, 0>(c_part, W_up, CU9, c_lds, t, m, 0);
  else if (l == 1) k_cu_body<3, 1>(c_part, W_up, CU9, c_lds, t, m, 1);
  else             k_cu_body<5, 4>(c_part, W_up, CU9, c_lds, t, m, 2);
}

// ---------------------------------------------------------------------------
// K4 (exact R0/R3 v1): split-K 8 (16 m's per block, two 72-K chunks).
// Block tile 32n x 128w, thread tile 4n x 4w; grid (64, 8) = 512 blocks.
// At/Bl reads are (near-)broadcasts -- cheap; keep in LDS.
// ---------------------------------------------------------------------------
__global__ __launch_bounds__(256) void k_up(const float* __restrict__ gc,
    const float* __restrict__ cc, const float* __restrict__ CU9,
    float* __restrict__ out_part) {
  __shared__ float At[72 * 36];   // [mrel*9+li][n_loc 0..31]
  __shared__ float Bl[72 * 128];  // [k][w]
  int t = threadIdx.x;
  int n0 = blockIdx.x * 32;
  int ks = blockIdx.y;            // 0..7
  int wq  = t & 31;               // w0 = 4*wq
  int tgn = t >> 5;               // 0..7, n_loc0 = 4*tgn
  int w0 = wq * 4;
  float acc[4][4] = {};

  for (int ch = 0; ch < 2; ++ch) {
    int m0 = ks*16 + ch*8;
    if (ch) __syncthreads();
    {
      int n_loc = t >> 3, mrel = t & 7;
      int n = n0 + n_loc, m = m0 + mrel;
      float dx = gc[3*n]   - cc[3*m];
      float dy = gc[3*n+1] - cc[3*m+1];
      float dz = gc[3*n+2] - cc[3*m+2];
      float d2 = dx*dx + dy*dy + dz*dz + 3e-20f;
      float inv = rsqrtf(d2);
      float x = dx*inv, y = dy*inv, z = dz*inv;
      const float s3 = 1.73205080757f;
      float sh[9];
      sh[0] = 1.0f; sh[1] = x; sh[2] = y; sh[3] = z;
      sh[4] = s3*x*z; sh[5] = s3*x*y; sh[6] = y*y - 0.5f*(x*x + z*z);
      sh[7] = s3*y*z; sh[8] = 0.5f*s3*(z*z - x*x);
      #pragma unroll
      for (int li = 0; li < 9; ++li)
        At[(mrel*9 + li)*36 + n_loc] = sh[li];
    }
    #pragma unroll
    for (int i = 0; i < 9; ++i) {
      int idx = t + i*256;
      *(float4*)&Bl[idx*4] = *(const float4*)(CU9 + (size_t)m0*9*H + idx*4);
    }
    __syncthreads();

    #pragma unroll 8
    for (int k = 0; k < 72; ++k) {
      float4 a = *(const float4*)&At[k*36 + 4*tgn];
      float4 b = *(const float4*)&Bl[k*128 + w0];
      float av[4] = {a.x, a.y, a.z, a.w};
      float bv[4] = {b.x, b.y, b.z, b.w};
      #pragma unroll
      for (int r = 0; r < 4; ++r)
        #pragma unroll
        for (int c = 0; c < 4; ++c)
          acc[r][c] += av[r] * bv[c];
    }
  }
  #pragma unroll
  for (int r = 0; r < 4; ++r) {
    size_t row = (size_t)ks*N_PTS + n0 + 4*tgn + r;
    *(float4*)(out_part + row*H + w0) =
        make_float4(acc[r][0], acc[r][1], acc[r][2], acc[r][3]);
  }
}

// ---------------------------------------------------------------------------
// K5: reduce 8 split-K partials, post-MLP + silu -> d_out.
// ---------------------------------------------------------------------------
__global__ __launch_bounds__(256) void k_post(const float* __restrict__ out_part,
    const float* __restrict__ W_post, const float* __restrict__ b_post,
    float* __restrict__ out) {
  __shared__ float op[4 * H];
  int t = threadIdx.x;
  int n0 = blockIdx.x * 4;
  int w = t & 127, nh = t >> 7;

  #pragma unroll
  for (int i = 0; i < 2; ++i) {
    int idx = t + i*256;
    int nl = idx >> 7, ww = idx & 127;
    float v = 0.0f;
    #pragma unroll
    for (int s = 0; s < 8; ++s)
      v += out_part[((size_t)s*N_PTS + n0 + nl)*H + ww];
    op[nl*H + ww] = v;
  }
  __syncthreads();

  float acc[2] = {0.0f, 0.0f};
  for (int u = 0; u < H; u += 4) {
    float4 p0 = *(const float4*)&op[(nh*2 + 0)*H + u];
    float4 p1 = *(const float4*)&op[(nh*2 + 1)*H + u];
    float w0 = W_post[(u+0)*H + w];
    float w1 = W_post[(u+1)*H + w];
    float w2 = W_post[(u+2)*H + w];
    float w3 = W_post[(u+3)*H + w];
    acc[0] += p0.x*w0 + p0.y*w1 + p0.z*w2 + p0.w*w3;
    acc[1] += p1.x*w0 + p1.y*w1 + p1.z*w2 + p1.w*w3;
  }
  float bp = b_post[w];
  out[(size_t)(n0 + nh*2 + 0)*H + w] = silu_f(acc[0] + bp);
  out[(size_t)(n0 + nh*2 + 1)*H + w] = silu_f(acc[1] + bp);
}

// ---------------------------------------------------------------------------
extern "C" void kernel_launch(void* const* d_in, const int* in_sizes, int n_in,
                              void* d_out, int out_size, void* d_ws, size_t ws_size,
                              hipStream_t stream) {
  const float* h      = (const float*)d_in[0];
  const float* gc     = (const float*)d_in[1];
  const float* cc     = (const float*)d_in[2];
  const float* gw     = (const float*)d_in[3];
  const float* W_pre  = (const float*)d_in[4];
  const float* b_pre  = (const float*)d_in[5];
  const float* W_down = (const float*)d_in[6];
  const float* W_up   = (const float*)d_in[7];
  const float* W_post = (const float*)d_in[8];
  const float* b_post = (const float*)d_in[9];

  float* ws       = (float*)d_ws;
  float* hdg4     = ws;                     // 2048*128*4   = 1,048,576 f
  float* c_part   = hdg4 + 1048576;         // 16*128*9*128 = 2,359,296 f
  float* CU9      = c_part + 2359296;       // 128*9*128    =   147,456 f
  float* out_part = c_part;                 // 8*2048*128 = 2,097,152 f aliases
  float* out      = (float*)d_out;

  k_pre <<<256,           256, 0, stream>>>(h, W_pre, b_pre, W_down, gw, hdg4);
  k_down<<<dim3(32,16),   256, 0, stream>>>(gc, cc, hdg4, c_part);
  k_cu  <<<dim3(128,3),   128, 0, stream>>>(c_part, W_up, CU9);
  k_up  <<<dim3(64,8),    256, 0, stream>>>(gc, cc, CU9, out_part);
  k_post<<<512,           256, 0, stream>>>(out_part, W_post, b_post, out);
}

// Round 6
// 135.365 us; speedup vs baseline: 1.1245x; 1.0303x over previous
//
#include <hip/hip_runtime.h>
#include <math.h>

#define N_PTS 2048
#define M_PTS 128
#define INNF  256
#define H     128

#define MIN_STDC 0.30235680f   /* 0.32*1.88973/2 */
#define MAX_STDC 2.19208680f   /* 2.32*1.88973/2 */
#define PI_F     3.14159265358979f
#define LOG2E_F  1.44269504089f

static __device__ __forceinline__ float silu_f(float x) {
  return x / (1.0f + __expf(-x));
}

// ---------------------------------------------------------------------------
// K1 v2 (R3 best): split-K across the 8 half-wave k-slices (kw = t>>5).
// One W ds_read_b128 feeds 32 FMA. 256 blocks.
// ---------------------------------------------------------------------------
__global__ __launch_bounds__(256) void k_pre(const float* __restrict__ h,
    const float* __restrict__ W_pre, const float* __restrict__ b_pre,
    const float* __restrict__ W_down, const float* __restrict__ gw,
    float* __restrict__ hdg4) {
  __shared__ float bigW[12288];
  __shared__ float red[8192];
  __shared__ float h_t[8 * INNF];
  __shared__ float hp_t[8 * H];
  int t = threadIdx.x;
  int n0 = blockIdx.x * 8;
  int wq = t & 31;
  int kw = t >> 5;
  int w0 = wq * 4;

  #pragma unroll
  for (int i = 0; i < 2; ++i) {
    int idx = t + i * 256;
    int row = idx >> 6, col = (idx & 63) << 2;
    *(float4*)&h_t[row * INNF + col] =
        *(const float4*)(h + (size_t)(n0 + row) * INNF + col);
  }

  // ---- GEMM1: hp = silu(h @ W_pre + b), k-split over kw ----
  float acc[8][4] = {};
  for (int kc = 0; kc < 256; kc += 64) {
    __syncthreads();
    #pragma unroll
    for (int i = 0; i < 8; ++i) {
      int idx = t + i * 256;
      *(float4*)&bigW[idx * 4] = *(const float4*)(W_pre + (size_t)kc * H + idx * 4);
    }
    __syncthreads();
    #pragma unroll
    for (int kk4 = 0; kk4 < 2; ++kk4) {
      int kb = kw * 8 + kk4 * 4;
      float4 hv[8];
      #pragma unroll
      for (int n = 0; n < 8; ++n)
        hv[n] = *(const float4*)&h_t[n * INNF + kc + kb];
      #pragma unroll
      for (int kk = 0; kk < 4; ++kk) {
        float4 wv = *(const float4*)&bigW[(kb + kk) * H + w0];
        #pragma unroll
        for (int n = 0; n < 8; ++n) {
          float hval = (kk == 0) ? hv[n].x : (kk == 1) ? hv[n].y
                     : (kk == 2) ? hv[n].z : hv[n].w;
          acc[n][0] += hval * wv.x; acc[n][1] += hval * wv.y;
          acc[n][2] += hval * wv.z; acc[n][3] += hval * wv.w;
        }
      }
    }
  }
  __syncthreads();
  #pragma unroll
  for (int n = 0; n < 8; ++n)
    *(float4*)&red[(kw * 8 + n) * 128 + w0] =
        make_float4(acc[n][0], acc[n][1], acc[n][2], acc[n][3]);
  __syncthreads();
  {
    int rn = t >> 5, rw = t & 31;
    float4 s = make_float4(0.0f, 0.0f, 0.0f, 0.0f);
    #pragma unroll
    for (int k2 = 0; k2 < 8; ++k2) {
      float4 v = *(const float4*)&red[(k2 * 8 + rn) * 128 + rw * 4];
      s.x += v.x; s.y += v.y; s.z += v.z; s.w += v.w;
    }
    float4 bv = *(const float4*)(b_pre + rw * 4);
    float4 o = make_float4(silu_f(s.x + bv.x), silu_f(s.y + bv.y),
                           silu_f(s.z + bv.z), silu_f(s.w + bv.w));
    *(float4*)&hp_t[rn * H + rw * 4] = o;
  }

  // ---- GEMM2: hp @ W_down[l], k-split over kw ----
  float acc2[3][8][4] = {};
  for (int kc = 0; kc < 128; kc += 32) {
    __syncthreads();
    #pragma unroll
    for (int i = 0; i < 12; ++i) {
      int idx = t + i * 256;
      int l = idx >> 10, r4 = idx & 1023;
      *(float4*)&bigW[idx * 4] =
          *(const float4*)(W_down + ((size_t)l * H + kc) * H + r4 * 4);
    }
    __syncthreads();
    {
      int kb = kw * 4;
      float4 hv[8];
      #pragma unroll
      for (int n = 0; n < 8; ++n)
        hv[n] = *(const float4*)&hp_t[n * H + kc + kb];
      #pragma unroll
      for (int kk = 0; kk < 4; ++kk) {
        #pragma unroll
        for (int l = 0; l < 3; ++l) {
          float4 wv = *(const float4*)&bigW[(l * 32 + kb + kk) * H + w0];
          #pragma unroll
          for (int n = 0; n < 8; ++n) {
            float hval = (kk == 0) ? hv[n].x : (kk == 1) ? hv[n].y
                       : (kk == 2) ? hv[n].z : hv[n].w;
            acc2[l][n][0] += hval * wv.x; acc2[l][n][1] += hval * wv.y;
            acc2[l][n][2] += hval * wv.z; acc2[l][n][3] += hval * wv.w;
          }
        }
      }
    }
  }

  __syncthreads();
  if (kw >= 4) {
    int s4 = kw - 4;
    #pragma unroll
    for (int l = 0; l < 3; ++l)
      #pragma unroll
      for (int n = 0; n < 8; ++n)
        *(float4*)&bigW[(s4 * 24 + l * 8 + n) * 128 + w0] =
            make_float4(acc2[l][n][0], acc2[l][n][1],
                        acc2[l][n][2], acc2[l][n][3]);
  }
  __syncthreads();
  if (kw < 4) {
    #pragma unroll
    for (int l = 0; l < 3; ++l)
      #pragma unroll
      for (int n = 0; n < 8; ++n) {
        float4 v = *(const float4*)&bigW[(kw * 24 + l * 8 + n) * 128 + w0];
        acc2[l][n][0] += v.x; acc2[l][n][1] += v.y;
        acc2[l][n][2] += v.z; acc2[l][n][3] += v.w;
      }
    if (kw >= 2) {
      int s2 = kw - 2;
      #pragma unroll
      for (int l = 0; l < 3; ++l)
        #pragma unroll
        for (int n = 0; n < 8; ++n)
          *(float4*)&red[(s2 * 24 + l * 8 + n) * 128 + w0] =
              make_float4(acc2[l][n][0], acc2[l][n][1],
                          acc2[l][n][2], acc2[l][n][3]);
    }
  }
  __syncthreads();
  if (kw < 2) {
    #pragma unroll
    for (int l = 0; l < 3; ++l)
      #pragma unroll
      for (int n = 0; n < 8; ++n) {
        float4 v = *(const float4*)&red[(kw * 24 + l * 8 + n) * 128 + w0];
        acc2[l][n][0] += v.x; acc2[l][n][1] += v.y;
        acc2[l][n][2] += v.z; acc2[l][n][3] += v.w;
      }
    if (kw == 1) {
      #pragma unroll
      for (int l = 0; l < 3; ++l)
        #pragma unroll
        for (int n = 0; n < 8; ++n)
          *(float4*)&bigW[(l * 8 + n) * 128 + w0] =
              make_float4(acc2[l][n][0], acc2[l][n][1],
                          acc2[l][n][2], acc2[l][n][3]);
    }
  }
  __syncthreads();
  if (kw == 0) {
    #pragma unroll
    for (int l = 0; l < 3; ++l)
      #pragma unroll
      for (int n = 0; n < 8; ++n) {
        float4 v = *(const float4*)&bigW[(l * 8 + n) * 128 + w0];
        acc2[l][n][0] += v.x; acc2[l][n][1] += v.y;
        acc2[l][n][2] += v.z; acc2[l][n][3] += v.w;
      }
    float gvals[8];
    #pragma unroll
    for (int n = 0; n < 8; ++n)
      gvals[n] = gw[n0 + n];
    const float stp = (MAX_STDC - MIN_STDC) / 127.0f;
    const float invn1 = 0.57735026919f, invn2 = 0.44721359550f;
    #pragma unroll
    for (int i = 0; i < 4; ++i) {
      int w = w0 + i;
      float s = MIN_STDC + (float)w * stp;
      float temps = 2.0f * s * s;
      float coef = (2.0f / 3.0f) / (temps * powf(PI_F * temps, 1.5f));
      #pragma unroll
      for (int n = 0; n < 8; ++n) {
        float sc = gvals[n] * coef;
        *(float4*)(hdg4 + ((size_t)(n0 + n) * H + w) * 4) =
            make_float4(acc2[0][n][i] * sc, acc2[1][n][i] * sc * invn1,
                        acc2[2][n][i] * sc * invn2, 0.0f);
      }
    }
  }
}

// ---------------------------------------------------------------------------
// K2 (R3 best, v4): pair loop, 128 n per block (16 s-slices). 2 w per lane;
// 4 waves each own a private 32-n subchunk; 2-stage LDS tree reduce.
// grid (32 mg, 16 s) = 512 blocks, 60 KB LDS -> 2 blocks/CU. sh reads are
// wave-uniform broadcasts (cheap) -- do NOT trade them for global reads.
// ---------------------------------------------------------------------------
__global__ __launch_bounds__(256) void k_down(const float* __restrict__ gc,
    const float* __restrict__ cc, const float* __restrict__ hdg4,
    float* __restrict__ c_part) {
  __shared__ float sh_t[6144];    // [n_loc 0..127][m_loc 0..3][12]
  __shared__ float red[9216];     // 2 x 4608 tree-reduce buffers
  int t = threadIdx.x;
  int m0 = blockIdx.x * 4;
  int ss = blockIdx.y;            // 0..15
  int n0 = ss * 128;
  int wv = t >> 6;
  int ln = t & 63;
  int w0 = ln * 2;

  // phase 0: SH tile (128n x 4m) = 512 pairs, 2 per thread
  #pragma unroll
  for (int i = 0; i < 2; ++i) {
    int idx = t + i * 256;
    int n_loc = idx >> 2, m_loc = idx & 3;
    int n = n0 + n_loc, m = m0 + m_loc;
    float dx = gc[3*n]   - cc[3*m];
    float dy = gc[3*n+1] - cc[3*m+1];
    float dz = gc[3*n+2] - cc[3*m+2];
    float d2 = dx*dx + dy*dy + dz*dz + 3e-20f;
    float inv = rsqrtf(d2);
    float x = dx*inv, y = dy*inv, z = dz*inv;
    const float s3 = 1.73205080757f;
    float* dst = &sh_t[(size_t)idx * 12];
    dst[0] = 1.0f; dst[1] = x; dst[2] = y; dst[3] = z;
    dst[4] = s3*x*z; dst[5] = s3*x*y; dst[6] = y*y - 0.5f*(x*x + z*z);
    dst[7] = s3*y*z; dst[8] = 0.5f*s3*(z*z - x*x);
    dst[9] = d2; dst[10] = 0.0f; dst[11] = 0.0f;
  }
  __syncthreads();

  const float stp = (MAX_STDC - MIN_STDC) / 127.0f;
  float sA = MIN_STDC + (float)w0 * stp;
  float sB = MIN_STDC + (float)(w0 + 1) * stp;
  float cA = -LOG2E_F / (2.0f * sA * sA);
  float cB = -LOG2E_F / (2.0f * sB * sB);

  float acc[4][9][2] = {};
  for (int j = 0; j < 32; ++j) {
    int nl = wv * 32 + j;
    const float4* hb = (const float4*)(hdg4 + ((size_t)(n0 + nl) * H + w0) * 4);
    float4 hv0 = hb[0];
    float4 hv1 = hb[1];
    const float* shb = &sh_t[(size_t)nl * 48];
    #pragma unroll
    for (int mm = 0; mm < 4; ++mm) {
      float4 q0 = *(const float4*)(shb + mm*12);
      float4 q1 = *(const float4*)(shb + mm*12 + 4);
      float4 q2 = *(const float4*)(shb + mm*12 + 8);
      float e0 = exp2f(q2.y * cA);
      float e1 = exp2f(q2.y * cB);
      float rp0 = e0 * q2.y, rp1 = e1 * q2.y;
      float a00 = hv0.x*rp0, a01 = hv0.y*rp0, a02 = hv0.z*rp0;
      float a10 = hv1.x*rp1, a11 = hv1.y*rp1, a12 = hv1.z*rp1;
      acc[mm][0][0] += a00;        acc[mm][0][1] += a10;
      acc[mm][1][0] += a01*q0.y;   acc[mm][1][1] += a11*q0.y;
      acc[mm][2][0] += a01*q0.z;   acc[mm][2][1] += a11*q0.z;
      acc[mm][3][0] += a01*q0.w;   acc[mm][3][1] += a11*q0.w;
      acc[mm][4][0] += a02*q1.x;   acc[mm][4][1] += a12*q1.x;
      acc[mm][5][0] += a02*q1.y;   acc[mm][5][1] += a12*q1.y;
      acc[mm][6][0] += a02*q1.z;   acc[mm][6][1] += a12*q1.z;
      acc[mm][7][0] += a02*q1.w;   acc[mm][7][1] += a12*q1.w;
      acc[mm][8][0] += a02*q2.x;   acc[mm][8][1] += a12*q2.x;
    }
  }

  __syncthreads();
  if (wv & 1) {
    float* dst = &red[(wv >> 1) * 4608];
    #pragma unroll
    for (int mm = 0; mm < 4; ++mm)
      #pragma unroll
      for (int li = 0; li < 9; ++li)
        *(float2*)&dst[(mm*9 + li)*128 + w0] =
            make_float2(acc[mm][li][0], acc[mm][li][1]);
  }
  __syncthreads();
  if (!(wv & 1)) {
    const float* src = &red[(wv >> 1) * 4608];
    #pragma unroll
    for (int mm = 0; mm < 4; ++mm)
      #pragma unroll
      for (int li = 0; li < 9; ++li) {
        float2 v = *(const float2*)&src[(mm*9 + li)*128 + w0];
        acc[mm][li][0] += v.x; acc[mm][li][1] += v.y;
      }
  }
  __syncthreads();
  if (wv == 2) {
    #pragma unroll
    for (int mm = 0; mm < 4; ++mm)
      #pragma unroll
      for (int li = 0; li < 9; ++li)
        *(float2*)&red[(mm*9 + li)*128 + w0] =
            make_float2(acc[mm][li][0], acc[mm][li][1]);
  }
  __syncthreads();
  if (wv == 0) {
    #pragma unroll
    for (int mm = 0; mm < 4; ++mm)
      #pragma unroll
      for (int li = 0; li < 9; ++li) {
        float2 v = *(const float2*)&red[(mm*9 + li)*128 + w0];
        float2 o = make_float2(acc[mm][li][0] + v.x, acc[mm][li][1] + v.y);
        *(float2*)&c_part[(((size_t)ss*M_PTS + m0 + mm)*9 + li)*H + w0] = o;
      }
  }
}

// ---------------------------------------------------------------------------
// K3 (R3 best, v1): block = (m, li): sum 16 s-partials over u, contract
// with W_up. grid (128, 9) = 1152 blocks, 128 threads.
// ---------------------------------------------------------------------------
__global__ __launch_bounds__(128) void k_cu(const float* __restrict__ c_part,
    const float* __restrict__ W_up, float* __restrict__ CU9) {
  __shared__ float c_lds[H];
  int t = threadIdx.x;
  int m = blockIdx.x, li = blockIdx.y;
  float v = 0.0f;
  #pragma unroll
  for (int s = 0; s < 16; ++s)
    v += c_part[(((size_t)s*M_PTS + m)*9 + li)*H + t];
  c_lds[t] = v;
  __syncthreads();

  int l = (li == 0) ? 0 : (li < 4 ? 1 : 2);
  const float invn[3] = {1.0f, 0.57735026919f, 0.44721359550f};
  float acc = 0.0f;
  for (int u = 0; u < H; u += 4) {
    float w0 = W_up[((size_t)l*H + u + 0)*H + t];
    float w1 = W_up[((size_t)l*H + u + 1)*H + t];
    float w2 = W_up[((size_t)l*H + u + 2)*H + t];
    float w3 = W_up[((size_t)l*H + u + 3)*H + t];
    acc += c_lds[u]*w0 + c_lds[u+1]*w1 + c_lds[u+2]*w2 + c_lds[u+3]*w3;
  }
  CU9[((size_t)m*9 + li)*H + t] = acc * invn[l];
}

// ---------------------------------------------------------------------------
// K4 (R3 best, v1): split-K 8 (16 m's per block, two 72-K chunks).
// Block tile 32n x 128w, thread tile 4n x 4w; grid (64, 8) = 512 blocks.
// At/Bl reads are few-address LDS reads -- cheap; keep in LDS.
// ---------------------------------------------------------------------------
__global__ __launch_bounds__(256) void k_up(const float* __restrict__ gc,
    const float* __restrict__ cc, const float* __restrict__ CU9,
    float* __restrict__ out_part) {
  __shared__ float At[72 * 36];   // [mrel*9+li][n_loc 0..31]
  __shared__ float Bl[72 * 128];  // [k][w]
  int t = threadIdx.x;
  int n0 = blockIdx.x * 32;
  int ks = blockIdx.y;            // 0..7
  int wq  = t & 31;               // w0 = 4*wq
  int tgn = t >> 5;               // 0..7, n_loc0 = 4*tgn
  int w0 = wq * 4;
  float acc[4][4] = {};

  for (int ch = 0; ch < 2; ++ch) {
    int m0 = ks*16 + ch*8;
    if (ch) __syncthreads();
    {
      int n_loc = t >> 3, mrel = t & 7;
      int n = n0 + n_loc, m = m0 + mrel;
      float dx = gc[3*n]   - cc[3*m];
      float dy = gc[3*n+1] - cc[3*m+1];
      float dz = gc[3*n+2] - cc[3*m+2];
      float d2 = dx*dx + dy*dy + dz*dz + 3e-20f;
      float inv = rsqrtf(d2);
      float x = dx*inv, y = dy*inv, z = dz*inv;
      const float s3 = 1.73205080757f;
      float sh[9];
      sh[0] = 1.0f; sh[1] = x; sh[2] = y; sh[3] = z;
      sh[4] = s3*x*z; sh[5] = s3*x*y; sh[6] = y*y - 0.5f*(x*x + z*z);
      sh[7] = s3*y*z; sh[8] = 0.5f*s3*(z*z - x*x);
      #pragma unroll
      for (int li = 0; li < 9; ++li)
        At[(mrel*9 + li)*36 + n_loc] = sh[li];
    }
    #pragma unroll
    for (int i = 0; i < 9; ++i) {
      int idx = t + i*256;
      *(float4*)&Bl[idx*4] = *(const float4*)(CU9 + (size_t)m0*9*H + idx*4);
    }
    __syncthreads();

    #pragma unroll 8
    for (int k = 0; k < 72; ++k) {
      float4 a = *(const float4*)&At[k*36 + 4*tgn];
      float4 b = *(const float4*)&Bl[k*128 + w0];
      float av[4] = {a.x, a.y, a.z, a.w};
      float bv[4] = {b.x, b.y, b.z, b.w};
      #pragma unroll
      for (int r = 0; r < 4; ++r)
        #pragma unroll
        for (int c = 0; c < 4; ++c)
          acc[r][c] += av[r] * bv[c];
    }
  }
  #pragma unroll
  for (int r = 0; r < 4; ++r) {
    size_t row = (size_t)ks*N_PTS + n0 + 4*tgn + r;
    *(float4*)(out_part + row*H + w0) =
        make_float4(acc[r][0], acc[r][1], acc[r][2], acc[r][3]);
  }
}

// ---------------------------------------------------------------------------
// K5: reduce 8 split-K partials, post-MLP + silu -> d_out.
// ---------------------------------------------------------------------------
__global__ __launch_bounds__(256) void k_post(const float* __restrict__ out_part,
    const float* __restrict__ W_post, const float* __restrict__ b_post,
    float* __restrict__ out) {
  __shared__ float op[4 * H];
  int t = threadIdx.x;
  int n0 = blockIdx.x * 4;
  int w = t & 127, nh = t >> 7;

  #pragma unroll
  for (int i = 0; i < 2; ++i) {
    int idx = t + i*256;
    int nl = idx >> 7, ww = idx & 127;
    float v = 0.0f;
    #pragma unroll
    for (int s = 0; s < 8; ++s)
      v += out_part[((size_t)s*N_PTS + n0 + nl)*H + ww];
    op[nl*H + ww] = v;
  }
  __syncthreads();

  float acc[2] = {0.0f, 0.0f};
  for (int u = 0; u < H; u += 4) {
    float4 p0 = *(const float4*)&op[(nh*2 + 0)*H + u];
    float4 p1 = *(const float4*)&op[(nh*2 + 1)*H + u];
    float w0 = W_post[(u+0)*H + w];
    float w1 = W_post[(u+1)*H + w];
    float w2 = W_post[(u+2)*H + w];
    float w3 = W_post[(u+3)*H + w];
    acc[0] += p0.x*w0 + p0.y*w1 + p0.z*w2 + p0.w*w3;
    acc[1] += p1.x*w0 + p1.y*w1 + p1.z*w2 + p1.w*w3;
  }
  float bp = b_post[w];
  out[(size_t)(n0 + nh*2 + 0)*H + w] = silu_f(acc[0] + bp);
  out[(size_t)(n0 + nh*2 + 1)*H + w] = silu_f(acc[1] + bp);
}

// ---------------------------------------------------------------------------
extern "C" void kernel_launch(void* const* d_in, const int* in_sizes, int n_in,
                              void* d_out, int out_size, void* d_ws, size_t ws_size,
                              hipStream_t stream) {
  const float* h      = (const float*)d_in[0];
  const float* gc     = (const float*)d_in[1];
  const float* cc     = (const float*)d_in[2];
  const float* gw     = (const float*)d_in[3];
  const float* W_pre  = (const float*)d_in[4];
  const float* b_pre  = (const float*)d_in[5];
  const float* W_down = (const float*)d_in[6];
  const float* W_up   = (const float*)d_in[7];
  const float* W_post = (const float*)d_in[8];
  const float* b_post = (const float*)d_in[9];

  float* ws       = (float*)d_ws;
  float* hdg4     = ws;                     // 2048*128*4   = 1,048,576 f
  float* c_part   = hdg4 + 1048576;         // 16*128*9*128 = 2,359,296 f
  float* CU9      = c_part + 2359296;       // 128*9*128    =   147,456 f
  float* out_part = c_part;                 // 8*2048*128 = 2,097,152 f aliases
  float* out      = (float*)d_out;

  k_pre <<<256,           256, 0, stream>>>(h, W_pre, b_pre, W_down, gw, hdg4);
  k_down<<<dim3(32,16),   256, 0, stream>>>(gc, cc, hdg4, c_part);
  k_cu  <<<dim3(128,9),   128, 0, stream>>>(c_part, W_up, CU9);
  k_up  <<<dim3(64,8),    256, 0, stream>>>(gc, cc, CU9, out_part);
  k_post<<<512,           256, 0, stream>>>(out_part, W_post, b_post, out);
}